// Round 27
// baseline (466.653 us; speedup 1.0000x reference)
//
#include <hip/hip_runtime.h>

#define G 3
#define K 40
#define S 1024
#define NB 32
#define CH 30
#define T 16384
#define TP 4096
#define M 131072           // NB*TP
#define CT (CH*T)          // 491520
#define OUT_Q (NB*CH*T)    // 15728640
#define MARGIN 4e-3f
#define FLAGBIT 0x40000000u

typedef __attribute__((ext_vector_type(8))) short short8;
typedef __attribute__((ext_vector_type(4))) float f32x4;

// ---- workspace layout ----
#define WS_LOSS 0
#define WS_E2   64                        // float[3][1024] = 12288 B
#define WS_PX   12352                     // short8[3*64*4*64] = 786432 B (end 798784)

static __device__ __forceinline__ unsigned short f2bf(float f) {
    union { float f; unsigned int u; } v; v.f = f;
    unsigned int u = v.u;
    return (unsigned short)((u + 0x7fffu + ((u >> 16) & 1u)) >> 16);   // RNE
}
static __device__ __forceinline__ float bf2f(unsigned short h) {
    union { unsigned int u; float f; } v; v.u = ((unsigned int)h) << 16;
    return v.f;
}

// Slot map: kappa = 32*m + 8*lgrp + j over virtual K=128.
//   [0,40): (eh,xh)  [40,80): (el,xh)  [80,120): (eh,xl)  [120,128): 0

// ================= prep: packed split fragments (interleaved) + e2 + loss zero =================
__global__ void vq_prep_frag(const float* __restrict__ cb, short8* __restrict__ PX,
                             float* __restrict__ e2, double* __restrict__ loss) {
    int t = blockIdx.x * 256 + threadIdx.x;      // [0, 3*64*64)
    if (t == 0) *loss = 0.0;
    if (t >= G * 64 * 64) return;
    const int lane = t & 63;
    const int st   = (t >> 6) & 63;
    const int g    = t >> 12;
    const int lmod = lane & 15, lgrp = lane >> 4;
    const int s0   = st * 16;
    const float* cbg = cb + (size_t)g * S * K;

    if (lane < 16) {
        const float* row = cbg + (size_t)(s0 + lane) * K;
        float acc = 0.f;
        #pragma unroll
        for (int k = 0; k < K; ++k) acc = fmaf(row[k], row[k], acc);
        e2[g * S + s0 + lane] = -0.5f * acc;     // maximize D = x.e - 0.5||e||^2
    }

    // A-operand layout (rounds 4-26 verified): lane holds row = lane&15, k' = 8*lgrp + j
    const float* crow = cbg + (size_t)(s0 + lmod) * K;
    #pragma unroll
    for (int m = 0; m < 4; ++m) {
        short8 P;
        #pragma unroll
        for (int j = 0; j < 8; ++j) {
            int kap = 32 * m + 8 * lgrp + j;
            bool valid = kap < 120;
            int d = (kap < 40) ? kap : ((kap < 80) ? kap - 40 : kap - 80);
            float v = valid ? crow[d] : 0.f;
            unsigned short hh = f2bf(v);
            unsigned short ll = f2bf(v - bf2f(hh));
            bool low = (kap >= 40) && (kap < 80);
            P[j] = (short)(low ? ll : hh);
        }
        PX[(((size_t)(g * 64 + st)) * 4 + m) * 64 + lane] = P;
    }
}

// ==== Kernel A (search): 2-tile ping-pong, 6 blocks/CU for VALU-slot fill ====
__global__ __launch_bounds__(256, 6) void vq_search(
        const float* __restrict__ z, const short8* __restrict__ PX,
        const float* __restrict__ e2, float* __restrict__ out) {
    __shared__ float sE2[S];                    // 4 KB (only LDS)

    const int lane = threadIdx.x & 63;
    const int w    = threadIdx.x >> 6;
    const int g    = blockIdx.x >> 10;                      // 1024 blocks per group
    const int qbase = ((blockIdx.x & 1023) << 7) + (w << 5); // 32 queries per wave
    const int n    = qbase >> 12;
    const int tp0  = qbase & 4095;
    const int lmod = lane & 15, lgrp = lane >> 4;

    const float* zg  = z + (size_t)n * CT + (size_t)g * K * TP;
    const float* e2g = e2 + g * S;
    const short8* PXg = PX + ((size_t)g * 64) * 4 * 64;

    // ---- e2 into LDS (all threads) ----
    *(f32x4*)(sE2 + threadIdx.x * 4) = *(const f32x4*)(e2g + threadIdx.x * 4);

    // ---- packed x fragments in REGISTERS: 2 m-tiles of 16 queries ----
    short8 xq[2][4];
    #pragma unroll
    for (int mt = 0; mt < 2; ++mt) {
        int tp = tp0 + mt * 16 + lmod;
        #pragma unroll
        for (int m = 0; m < 4; ++m) {
            short8 xb;
            #pragma unroll
            for (int j = 0; j < 8; ++j) {
                int kap = 32 * m + 8 * lgrp + j;
                bool valid = kap < 120;
                int d = (kap < 40) ? kap : ((kap < 80) ? kap - 40 : kap - 80);
                float v = valid ? zg[(size_t)d * TP + tp] : 0.f;
                unsigned short hh = f2bf(v);
                unsigned short ll = f2bf(v - bf2f(hh));
                bool low = (kap >= 80) && (kap < 120);
                xb[j] = (short)(low ? ll : hh);
            }
            xq[mt][m] = xb;
        }
    }
    __syncthreads();    // sE2 visibility

    float v1[2], v2[2]; int i1[2];
    #pragma unroll
    for (int mt = 0; mt < 2; ++mt) { v1[mt] = -3.4e38f; v2[mt] = -3.4e38f; i1[mt] = 0; }

#define COMPTILE(c0_, c1_, c2_, c3_, st_)                                               \
    do {                                                                                \
        f32x4 e2v = *(const f32x4*)(sE2 + (st_) * 16 + lgrp * 4);                       \
        const int sbase = (st_) * 16 + lgrp * 4;                                        \
        _Pragma("unroll")                                                               \
        for (int mt = 0; mt < 2; ++mt) {                                                \
            f32x4 d = __builtin_amdgcn_mfma_f32_16x16x32_bf16(c0_, xq[mt][0], e2v, 0, 0, 0); \
            d = __builtin_amdgcn_mfma_f32_16x16x32_bf16(c1_, xq[mt][1], d, 0, 0, 0);    \
            d = __builtin_amdgcn_mfma_f32_16x16x32_bf16(c2_, xq[mt][2], d, 0, 0, 0);    \
            d = __builtin_amdgcn_mfma_f32_16x16x32_bf16(c3_, xq[mt][3], d, 0, 0, 0);    \
            _Pragma("unroll")                                                           \
            for (int j = 0; j < 4; ++j) {                                               \
                float sj = d[j];                                                        \
                v2[mt] = __builtin_amdgcn_fmed3f(v1[mt], v2[mt], sj);                   \
                bool cc = sj > v1[mt];                                                  \
                v1[mt] = fmaxf(v1[mt], sj);                                             \
                i1[mt] = cc ? (sbase + j) : i1[mt];                                     \
            }                                                                           \
        }                                                                               \
    } while (0)

    // ---- main loop: 32 iters x 2 tiles; static a/b buffers, no rotation movs ----
    short8 a0 = PXg[lane], a1 = PXg[64 + lane], a2 = PXg[128 + lane], a3 = PXg[192 + lane];
    short8 b0, b1, b2, b3;
    #pragma unroll 1
    for (int it = 0; it < 32; ++it) {
        const int st0 = 2 * it, st1 = 2 * it + 1;
        {
            const short8* pn = PXg + (size_t)st1 * 256 + lane;
            b0 = pn[0]; b1 = pn[64]; b2 = pn[128]; b3 = pn[192];
        }
        COMPTILE(a0, a1, a2, a3, st0);
        if (it < 31) {
            const short8* pn = PXg + (size_t)(st0 + 2) * 256 + lane;
            a0 = pn[0]; a1 = pn[64]; a2 = pn[128]; a3 = pn[192];
        }
        COMPTILE(b0, b1, b2, b3, st1);
    }
#undef COMPTILE

    // ---- cross-lane merge; write idx|flag straight to global (no LDS, no fp64) ----
    int* slotbase = (int*)(out + (size_t)n * CT + (size_t)g * K * TP);
    #pragma unroll
    for (int mt = 0; mt < 2; ++mt) {
        float a1v = v1[mt], a2v = v2[mt];
        int ii = i1[mt];
        #pragma unroll
        for (int off = 16; off < 64; off <<= 1) {
            float p1 = __shfl_xor(a1v, off);
            float p2 = __shfl_xor(a2v, off);
            int   pi = __shfl_xor(ii, off);
            float lo = fminf(a1v, p1);
            a2v = fmaxf(fmaxf(a2v, p2), lo);
            bool take = (p1 > a1v) || (p1 == a1v && pi < ii);
            ii = take ? pi : ii;
            a1v = fmaxf(a1v, p1);
        }
        if (lane < 16) {
            unsigned int val = (unsigned int)ii | ((a1v - a2v < MARGIN) ? FLAGBIT : 0u);
            slotbase[tp0 + mt * 16 + lane] = (int)val;
        }
    }
}

// ==== Kernel C (fixup): rare exact fp64 rescan, float4 loads + unrolled chains ====
__global__ __launch_bounds__(256, 2) void vq_fix(
        const float* __restrict__ z, const float* __restrict__ cb,
        float* __restrict__ out) {
    __shared__ float sXq[4][K];

    const int lane = threadIdx.x & 63;
    const int w    = threadIdx.x >> 6;
    const int gq0  = (blockIdx.x * 4 + w) * 64;     // first query of this wave
    const int g    = gq0 >> 17;                     // M = 2^17
    const int mm   = gq0 & (M - 1);
    const int n    = mm >> 12;
    const int tp0  = mm & 4095;

    const float* zg  = z + (size_t)n * CT + (size_t)g * K * TP;
    const float* cbg = cb + (size_t)g * S * K;
    int* slotbase = (int*)(out + (size_t)n * CT + (size_t)g * K * TP);

    unsigned int val = (unsigned int)slotbase[tp0 + lane];
    unsigned long long mask = __ballot((val & FLAGBIT) != 0u);
    while (mask) {
        int qq = __ffsll((unsigned long long)mask) - 1; mask &= mask - 1;
        int tpq = tp0 + qq;
        __threadfence_block();
        if (lane < K) sXq[w][lane] = zg[(size_t)lane * TP + tpq];
        __threadfence_block();
        double bestv = 1e300; int besti = 0;
        #pragma unroll 2
        for (int si = 0; si < 16; ++si) {
            int s = lane * 16 + si;
            const f32x4* cr4 = (const f32x4*)(cbg + (size_t)s * K);
            f32x4 cv[10];
            #pragma unroll
            for (int i = 0; i < 10; ++i) cv[i] = cr4[i];   // issue all loads up-front
            double acc = 0.0, en = 0.0;
            #pragma unroll
            for (int i = 0; i < 10; ++i) {
                #pragma unroll
                for (int c = 0; c < 4; ++c) {
                    double ev = (double)cv[i][c];
                    acc = fma(ev, (double)sXq[w][i * 4 + c], acc);
                    en  = fma(ev, ev, en);
                }
            }
            double sc = 0.5 * en - acc;
            if (sc < bestv) { bestv = sc; besti = s; }
        }
        #pragma unroll
        for (int off = 1; off < 64; off <<= 1) {
            double pv = __shfl_xor(bestv, off);
            int    pi = __shfl_xor(besti, off);
            if (pv < bestv || (pv == bestv && pi < besti)) { bestv = pv; besti = pi; }
        }
        if (lane == 0) slotbase[tpq] = besti;       // clears flag
    }
}

// ==== Kernel B (gather): one thread per query; float4 codeword loads ====
__global__ __launch_bounds__(256) void vq_gather(
        const float* __restrict__ z, const float* __restrict__ cb,
        float* __restrict__ out, double* __restrict__ loss) {
    const int q = blockIdx.x * 256 + threadIdx.x;   // [0, 3*M)
    const int g = q >> 17;                          // M = 2^17
    const int m = q & (M - 1);
    const int n = m >> 12;
    const int tp = m & 4095;

    float* base = out + (size_t)n * CT + (size_t)g * K * TP;
    const int idx = ((const int*)base)[tp] & 1023;
    const f32x4* cr4 = (const f32x4*)(cb + ((size_t)g * S + idx) * K);
    const float* zr = z + (size_t)n * CT + (size_t)g * K * TP + tp;

    f32x4 cv[10];
    #pragma unroll
    for (int i = 0; i < 10; ++i) cv[i] = cr4[i];    // issue all loads up-front

    double lsum = 0.0;
    #pragma unroll
    for (int i = 0; i < 10; ++i) {
        #pragma unroll
        for (int c = 0; c < 4; ++c) {
            const int k = i * 4 + c;
            float qv = cv[i][c];
            base[(size_t)k * TP + tp] = qv;
            if (g == 2) {
                float xv = zr[(size_t)k * TP];
                double dd = (double)qv - (double)xv;
                lsum = fma(dd, dd, lsum);
            }
        }
    }

    if (g == 2) {
        #pragma unroll
        for (int off = 1; off < 64; off <<= 1)
            lsum += __shfl_xor(lsum, off);
        if ((threadIdx.x & 63) == 0) atomicAdd(loss, lsum);
    }
}

// ---------------- finalize: scalar loss ----------------
__global__ void vq_fin_kernel(const double* __restrict__ loss, float* __restrict__ out) {
    out[OUT_Q] = (float)(0.25 * (*loss) / (double)((long long)M * K));
}

extern "C" void kernel_launch(void* const* d_in, const int* in_sizes, int n_in,
                              void* d_out, int out_size, void* d_ws, size_t ws_size,
                              hipStream_t stream) {
    const float* z  = (const float*)d_in[0];
    const float* cb = (const float*)d_in[1];
    float* out = (float*)d_out;

    char* ws = (char*)d_ws;
    double* loss = (double*)(ws + WS_LOSS);
    float*  e2   = (float*)(ws + WS_E2);
    short8* PX   = (short8*)(ws + WS_PX);

    vq_prep_frag<<<dim3(48), dim3(256), 0, stream>>>(cb, PX, e2, loss);
    vq_search<<<dim3(3072), dim3(256), 0, stream>>>(z, PX, e2, out);
    vq_fix<<<dim3((G * M) / 256), dim3(256), 0, stream>>>(z, cb, out);
    vq_gather<<<dim3((G * M) / 256), dim3(256), 0, stream>>>(z, cb, out, loss);
    vq_fin_kernel<<<dim3(1), dim3(1), 0, stream>>>(loss, out);
}

// Round 28
// 221.421 us; speedup vs baseline: 2.1075x; 2.1075x over previous
//
#include <hip/hip_runtime.h>

#define G 3
#define K 40
#define S 1024
#define NB 32
#define CH 30
#define T 16384
#define TP 4096
#define M 131072           // NB*TP
#define CT (CH*T)          // 491520
#define OUT_Q (NB*CH*T)    // 15728640
#define MARGIN 4e-3f
#define FLAGBIT 0x40000000u

typedef __attribute__((ext_vector_type(8))) short short8;
typedef __attribute__((ext_vector_type(4))) float f32x4;

// ---- workspace layout ----
#define WS_LOSS 0
#define WS_E2   64                        // float[3][1024] = 12288 B
#define WS_PX   12352                     // short8[3*64*4*64] = 786432 B (end 798784)

static __device__ __forceinline__ unsigned short f2bf(float f) {
    union { float f; unsigned int u; } v; v.f = f;
    unsigned int u = v.u;
    return (unsigned short)((u + 0x7fffu + ((u >> 16) & 1u)) >> 16);   // RNE
}
static __device__ __forceinline__ float bf2f(unsigned short h) {
    union { unsigned int u; float f; } v; v.u = ((unsigned int)h) << 16;
    return v.f;
}

// Slot map: kappa = 32*m + 8*lgrp + j over virtual K=128.
//   [0,40): (eh,xh)  [40,80): (el,xh)  [80,120): (eh,xl)  [120,128): 0

// ================= prep: packed split fragments (interleaved) + e2 + loss zero =================
__global__ void vq_prep_frag(const float* __restrict__ cb, short8* __restrict__ PX,
                             float* __restrict__ e2, double* __restrict__ loss) {
    int t = blockIdx.x * 256 + threadIdx.x;      // [0, 3*64*64)
    if (t == 0) *loss = 0.0;
    if (t >= G * 64 * 64) return;
    const int lane = t & 63;
    const int st   = (t >> 6) & 63;
    const int g    = t >> 12;
    const int lmod = lane & 15, lgrp = lane >> 4;
    const int s0   = st * 16;
    const float* cbg = cb + (size_t)g * S * K;

    if (lane < 16) {
        const float* row = cbg + (size_t)(s0 + lane) * K;
        float acc = 0.f;
        #pragma unroll
        for (int k = 0; k < K; ++k) acc = fmaf(row[k], row[k], acc);
        e2[g * S + s0 + lane] = -0.5f * acc;     // maximize D = x.e - 0.5||e||^2
    }

    // A-operand layout (rounds 4-26 verified): lane holds row = lane&15, k' = 8*lgrp + j
    const float* crow = cbg + (size_t)(s0 + lmod) * K;
    #pragma unroll
    for (int m = 0; m < 4; ++m) {
        short8 P;
        #pragma unroll
        for (int j = 0; j < 8; ++j) {
            int kap = 32 * m + 8 * lgrp + j;
            bool valid = kap < 120;
            int d = (kap < 40) ? kap : ((kap < 80) ? kap - 40 : kap - 80);
            float v = valid ? crow[d] : 0.f;
            unsigned short hh = f2bf(v);
            unsigned short ll = f2bf(v - bf2f(hh));
            bool low = (kap >= 40) && (kap < 80);
            P[j] = (short)(low ? ll : hh);
        }
        PX[(((size_t)(g * 64 + st)) * 4 + m) * 64 + lane] = P;
    }
}

// ==== Kernel A (search): r26-proven — 2-tile ping-pong, 4 blocks/CU ====
__global__ __launch_bounds__(256, 4) void vq_search(
        const float* __restrict__ z, const short8* __restrict__ PX,
        const float* __restrict__ e2, float* __restrict__ out) {
    __shared__ float sE2[S];                    // 4 KB (only LDS)

    const int lane = threadIdx.x & 63;
    const int w    = threadIdx.x >> 6;
    const int g    = blockIdx.x >> 10;                      // 1024 blocks per group
    const int qbase = ((blockIdx.x & 1023) << 7) + (w << 5); // 32 queries per wave
    const int n    = qbase >> 12;
    const int tp0  = qbase & 4095;
    const int lmod = lane & 15, lgrp = lane >> 4;

    const float* zg  = z + (size_t)n * CT + (size_t)g * K * TP;
    const float* e2g = e2 + g * S;
    const short8* PXg = PX + ((size_t)g * 64) * 4 * 64;

    // ---- e2 into LDS (all threads) ----
    *(f32x4*)(sE2 + threadIdx.x * 4) = *(const f32x4*)(e2g + threadIdx.x * 4);

    // ---- packed x fragments in REGISTERS: 2 m-tiles of 16 queries ----
    short8 xq[2][4];
    #pragma unroll
    for (int mt = 0; mt < 2; ++mt) {
        int tp = tp0 + mt * 16 + lmod;
        #pragma unroll
        for (int m = 0; m < 4; ++m) {
            short8 xb;
            #pragma unroll
            for (int j = 0; j < 8; ++j) {
                int kap = 32 * m + 8 * lgrp + j;
                bool valid = kap < 120;
                int d = (kap < 40) ? kap : ((kap < 80) ? kap - 40 : kap - 80);
                float v = valid ? zg[(size_t)d * TP + tp] : 0.f;
                unsigned short hh = f2bf(v);
                unsigned short ll = f2bf(v - bf2f(hh));
                bool low = (kap >= 80) && (kap < 120);
                xb[j] = (short)(low ? ll : hh);
            }
            xq[mt][m] = xb;
        }
    }
    __syncthreads();    // sE2 visibility

    float v1[2], v2[2]; int i1[2];
    #pragma unroll
    for (int mt = 0; mt < 2; ++mt) { v1[mt] = -3.4e38f; v2[mt] = -3.4e38f; i1[mt] = 0; }

#define COMPTILE(c0_, c1_, c2_, c3_, st_)                                               \
    do {                                                                                \
        f32x4 e2v = *(const f32x4*)(sE2 + (st_) * 16 + lgrp * 4);                       \
        const int sbase = (st_) * 16 + lgrp * 4;                                        \
        _Pragma("unroll")                                                               \
        for (int mt = 0; mt < 2; ++mt) {                                                \
            f32x4 d = __builtin_amdgcn_mfma_f32_16x16x32_bf16(c0_, xq[mt][0], e2v, 0, 0, 0); \
            d = __builtin_amdgcn_mfma_f32_16x16x32_bf16(c1_, xq[mt][1], d, 0, 0, 0);    \
            d = __builtin_amdgcn_mfma_f32_16x16x32_bf16(c2_, xq[mt][2], d, 0, 0, 0);    \
            d = __builtin_amdgcn_mfma_f32_16x16x32_bf16(c3_, xq[mt][3], d, 0, 0, 0);    \
            _Pragma("unroll")                                                           \
            for (int j = 0; j < 4; ++j) {                                               \
                float sj = d[j];                                                        \
                v2[mt] = __builtin_amdgcn_fmed3f(v1[mt], v2[mt], sj);                   \
                bool cc = sj > v1[mt];                                                  \
                v1[mt] = fmaxf(v1[mt], sj);                                             \
                i1[mt] = cc ? (sbase + j) : i1[mt];                                     \
            }                                                                           \
        }                                                                               \
    } while (0)

    // ---- main loop: 32 iters x 2 tiles; static a/b buffers, no rotation movs ----
    short8 a0 = PXg[lane], a1 = PXg[64 + lane], a2 = PXg[128 + lane], a3 = PXg[192 + lane];
    short8 b0, b1, b2, b3;
    #pragma unroll 1
    for (int it = 0; it < 32; ++it) {
        const int st0 = 2 * it, st1 = 2 * it + 1;
        {
            const short8* pn = PXg + (size_t)st1 * 256 + lane;
            b0 = pn[0]; b1 = pn[64]; b2 = pn[128]; b3 = pn[192];
        }
        COMPTILE(a0, a1, a2, a3, st0);
        if (it < 31) {
            const short8* pn = PXg + (size_t)(st0 + 2) * 256 + lane;
            a0 = pn[0]; a1 = pn[64]; a2 = pn[128]; a3 = pn[192];
        }
        COMPTILE(b0, b1, b2, b3, st1);
    }
#undef COMPTILE

    // ---- cross-lane merge; write idx|flag straight to global (no LDS, no fp64) ----
    int* slotbase = (int*)(out + (size_t)n * CT + (size_t)g * K * TP);
    #pragma unroll
    for (int mt = 0; mt < 2; ++mt) {
        float a1v = v1[mt], a2v = v2[mt];
        int ii = i1[mt];
        #pragma unroll
        for (int off = 16; off < 64; off <<= 1) {
            float p1 = __shfl_xor(a1v, off);
            float p2 = __shfl_xor(a2v, off);
            int   pi = __shfl_xor(ii, off);
            float lo = fminf(a1v, p1);
            a2v = fmaxf(fmaxf(a2v, p2), lo);
            bool take = (p1 > a1v) || (p1 == a1v && pi < ii);
            ii = take ? pi : ii;
            a1v = fmaxf(a1v, p1);
        }
        if (lane < 16) {
            unsigned int val = (unsigned int)ii | ((a1v - a2v < MARGIN) ? FLAGBIT : 0u);
            slotbase[tp0 + mt * 16 + lane] = (int)val;
        }
    }
}

// ==== Kernel C (fixup): rare exact fp64 rescan, float4 loads + unrolled chains ====
__global__ __launch_bounds__(256, 2) void vq_fix(
        const float* __restrict__ z, const float* __restrict__ cb,
        float* __restrict__ out) {
    __shared__ float sXq[4][K];

    const int lane = threadIdx.x & 63;
    const int w    = threadIdx.x >> 6;
    const int gq0  = (blockIdx.x * 4 + w) * 64;     // first query of this wave
    const int g    = gq0 >> 17;                     // M = 2^17
    const int mm   = gq0 & (M - 1);
    const int n    = mm >> 12;
    const int tp0  = mm & 4095;

    const float* zg  = z + (size_t)n * CT + (size_t)g * K * TP;
    const float* cbg = cb + (size_t)g * S * K;
    int* slotbase = (int*)(out + (size_t)n * CT + (size_t)g * K * TP);

    unsigned int val = (unsigned int)slotbase[tp0 + lane];
    unsigned long long mask = __ballot((val & FLAGBIT) != 0u);
    while (mask) {
        int qq = __ffsll((unsigned long long)mask) - 1; mask &= mask - 1;
        int tpq = tp0 + qq;
        __threadfence_block();
        if (lane < K) sXq[w][lane] = zg[(size_t)lane * TP + tpq];
        __threadfence_block();
        double bestv = 1e300; int besti = 0;
        #pragma unroll 2
        for (int si = 0; si < 16; ++si) {
            int s = lane * 16 + si;
            const f32x4* cr4 = (const f32x4*)(cbg + (size_t)s * K);
            f32x4 cv[10];
            #pragma unroll
            for (int i = 0; i < 10; ++i) cv[i] = cr4[i];   // issue all loads up-front
            double acc = 0.0, en = 0.0;
            #pragma unroll
            for (int i = 0; i < 10; ++i) {
                #pragma unroll
                for (int c = 0; c < 4; ++c) {
                    double ev = (double)cv[i][c];
                    acc = fma(ev, (double)sXq[w][i * 4 + c], acc);
                    en  = fma(ev, ev, en);
                }
            }
            double sc = 0.5 * en - acc;
            if (sc < bestv) { bestv = sc; besti = s; }
        }
        #pragma unroll
        for (int off = 1; off < 64; off <<= 1) {
            double pv = __shfl_xor(bestv, off);
            int    pi = __shfl_xor(besti, off);
            if (pv < bestv || (pv == bestv && pi < besti)) { bestv = pv; besti = pi; }
        }
        if (lane == 0) slotbase[tpq] = besti;       // clears flag
    }
}

// ==== Kernel B (gather): one thread per query; float4 codeword loads ====
__global__ __launch_bounds__(256) void vq_gather(
        const float* __restrict__ z, const float* __restrict__ cb,
        float* __restrict__ out, double* __restrict__ loss) {
    const int q = blockIdx.x * 256 + threadIdx.x;   // [0, 3*M)
    const int g = q >> 17;                          // M = 2^17
    const int m = q & (M - 1);
    const int n = m >> 12;
    const int tp = m & 4095;

    float* base = out + (size_t)n * CT + (size_t)g * K * TP;
    const int idx = ((const int*)base)[tp] & 1023;
    const f32x4* cr4 = (const f32x4*)(cb + ((size_t)g * S + idx) * K);
    const float* zr = z + (size_t)n * CT + (size_t)g * K * TP + tp;

    f32x4 cv[10];
    #pragma unroll
    for (int i = 0; i < 10; ++i) cv[i] = cr4[i];    // issue all loads up-front

    double lsum = 0.0;
    #pragma unroll
    for (int i = 0; i < 10; ++i) {
        #pragma unroll
        for (int c = 0; c < 4; ++c) {
            const int k = i * 4 + c;
            float qv = cv[i][c];
            base[(size_t)k * TP + tp] = qv;
            if (g == 2) {
                float xv = zr[(size_t)k * TP];
                double dd = (double)qv - (double)xv;
                lsum = fma(dd, dd, lsum);
            }
        }
    }

    if (g == 2) {
        #pragma unroll
        for (int off = 1; off < 64; off <<= 1)
            lsum += __shfl_xor(lsum, off);
        if ((threadIdx.x & 63) == 0) atomicAdd(loss, lsum);
    }
}

// ---------------- finalize: scalar loss ----------------
__global__ void vq_fin_kernel(const double* __restrict__ loss, float* __restrict__ out) {
    out[OUT_Q] = (float)(0.25 * (*loss) / (double)((long long)M * K));
}

extern "C" void kernel_launch(void* const* d_in, const int* in_sizes, int n_in,
                              void* d_out, int out_size, void* d_ws, size_t ws_size,
                              hipStream_t stream) {
    const float* z  = (const float*)d_in[0];
    const float* cb = (const float*)d_in[1];
    float* out = (float*)d_out;

    char* ws = (char*)d_ws;
    double* loss = (double*)(ws + WS_LOSS);
    float*  e2   = (float*)(ws + WS_E2);
    short8* PX   = (short8*)(ws + WS_PX);

    vq_prep_frag<<<dim3(48), dim3(256), 0, stream>>>(cb, PX, e2, loss);
    vq_search<<<dim3(3072), dim3(256), 0, stream>>>(z, PX, e2, out);
    vq_fix<<<dim3((G * M) / 256), dim3(256), 0, stream>>>(z, cb, out);
    vq_gather<<<dim3((G * M) / 256), dim3(256), 0, stream>>>(z, cb, out, loss);
    vq_fin_kernel<<<dim3(1), dim3(1), 0, stream>>>(loss, out);
}

// Round 29
// 216.170 us; speedup vs baseline: 2.1587x; 1.0243x over previous
//
#include <hip/hip_runtime.h>

#define G 3
#define K 40
#define S 1024
#define NB 32
#define CH 30
#define T 16384
#define TP 4096
#define M 131072           // NB*TP
#define CT (CH*T)          // 491520
#define OUT_Q (NB*CH*T)    // 15728640
#define MARGIN 4e-3f
#define FLAGBIT 0x40000000u

typedef __attribute__((ext_vector_type(8))) short short8;
typedef __attribute__((ext_vector_type(4))) float f32x4;

// ---- workspace layout ----
#define WS_LOSS 0
#define WS_E2   64                        // float[3][1024] = 12288 B
#define WS_PX   12352                     // short8[3*64*4*64] = 786432 B (end 798784)

static __device__ __forceinline__ unsigned short f2bf(float f) {
    union { float f; unsigned int u; } v; v.f = f;
    unsigned int u = v.u;
    return (unsigned short)((u + 0x7fffu + ((u >> 16) & 1u)) >> 16);   // RNE
}
static __device__ __forceinline__ float bf2f(unsigned short h) {
    union { unsigned int u; float f; } v; v.u = ((unsigned int)h) << 16;
    return v.f;
}

// Slot map: kappa = 32*m + 8*lgrp + j over virtual K=128.
//   [0,40): (eh,xh)  [40,80): (el,xh)  [80,120): (eh,xl)  [120,128): 0

// ================= prep: packed split fragments (interleaved) + e2 + loss zero =================
__global__ void vq_prep_frag(const float* __restrict__ cb, short8* __restrict__ PX,
                             float* __restrict__ e2, double* __restrict__ loss) {
    int t = blockIdx.x * 256 + threadIdx.x;      // [0, 3*64*64)
    if (t == 0) *loss = 0.0;
    if (t >= G * 64 * 64) return;
    const int lane = t & 63;
    const int st   = (t >> 6) & 63;
    const int g    = t >> 12;
    const int lmod = lane & 15, lgrp = lane >> 4;
    const int s0   = st * 16;
    const float* cbg = cb + (size_t)g * S * K;

    if (lane < 16) {
        const float* row = cbg + (size_t)(s0 + lane) * K;
        float acc = 0.f;
        #pragma unroll
        for (int k = 0; k < K; ++k) acc = fmaf(row[k], row[k], acc);
        e2[g * S + s0 + lane] = -0.5f * acc;     // maximize D = x.e - 0.5||e||^2
    }

    // A-operand layout (rounds 4-28 verified): lane holds row = lane&15, k' = 8*lgrp + j
    const float* crow = cbg + (size_t)(s0 + lmod) * K;
    #pragma unroll
    for (int m = 0; m < 4; ++m) {
        short8 P;
        #pragma unroll
        for (int j = 0; j < 8; ++j) {
            int kap = 32 * m + 8 * lgrp + j;
            bool valid = kap < 120;
            int d = (kap < 40) ? kap : ((kap < 80) ? kap - 40 : kap - 80);
            float v = valid ? crow[d] : 0.f;
            unsigned short hh = f2bf(v);
            unsigned short ll = f2bf(v - bf2f(hh));
            bool low = (kap >= 40) && (kap < 80);
            P[j] = (short)(low ? ll : hh);
        }
        PX[(((size_t)(g * 64 + st)) * 4 + m) * 64 + lane] = P;
    }
}

// ==== Kernel A (search): r26/r28-proven — 2-tile ping-pong, 4 blocks/CU ====
__global__ __launch_bounds__(256, 4) void vq_search(
        const float* __restrict__ z, const short8* __restrict__ PX,
        const float* __restrict__ e2, float* __restrict__ out) {
    __shared__ float sE2[S];                    // 4 KB (only LDS)

    const int lane = threadIdx.x & 63;
    const int w    = threadIdx.x >> 6;
    const int g    = blockIdx.x >> 10;                      // 1024 blocks per group
    const int qbase = ((blockIdx.x & 1023) << 7) + (w << 5); // 32 queries per wave
    const int n    = qbase >> 12;
    const int tp0  = qbase & 4095;
    const int lmod = lane & 15, lgrp = lane >> 4;

    const float* zg  = z + (size_t)n * CT + (size_t)g * K * TP;
    const float* e2g = e2 + g * S;
    const short8* PXg = PX + ((size_t)g * 64) * 4 * 64;

    // ---- e2 into LDS (all threads) ----
    *(f32x4*)(sE2 + threadIdx.x * 4) = *(const f32x4*)(e2g + threadIdx.x * 4);

    // ---- packed x fragments in REGISTERS: 2 m-tiles of 16 queries ----
    short8 xq[2][4];
    #pragma unroll
    for (int mt = 0; mt < 2; ++mt) {
        int tp = tp0 + mt * 16 + lmod;
        #pragma unroll
        for (int m = 0; m < 4; ++m) {
            short8 xb;
            #pragma unroll
            for (int j = 0; j < 8; ++j) {
                int kap = 32 * m + 8 * lgrp + j;
                bool valid = kap < 120;
                int d = (kap < 40) ? kap : ((kap < 80) ? kap - 40 : kap - 80);
                float v = valid ? zg[(size_t)d * TP + tp] : 0.f;
                unsigned short hh = f2bf(v);
                unsigned short ll = f2bf(v - bf2f(hh));
                bool low = (kap >= 80) && (kap < 120);
                xb[j] = (short)(low ? ll : hh);
            }
            xq[mt][m] = xb;
        }
    }
    __syncthreads();    // sE2 visibility

    float v1[2], v2[2]; int i1[2];
    #pragma unroll
    for (int mt = 0; mt < 2; ++mt) { v1[mt] = -3.4e38f; v2[mt] = -3.4e38f; i1[mt] = 0; }

#define COMPTILE(c0_, c1_, c2_, c3_, st_)                                               \
    do {                                                                                \
        f32x4 e2v = *(const f32x4*)(sE2 + (st_) * 16 + lgrp * 4);                       \
        const int sbase = (st_) * 16 + lgrp * 4;                                        \
        _Pragma("unroll")                                                               \
        for (int mt = 0; mt < 2; ++mt) {                                                \
            f32x4 d = __builtin_amdgcn_mfma_f32_16x16x32_bf16(c0_, xq[mt][0], e2v, 0, 0, 0); \
            d = __builtin_amdgcn_mfma_f32_16x16x32_bf16(c1_, xq[mt][1], d, 0, 0, 0);    \
            d = __builtin_amdgcn_mfma_f32_16x16x32_bf16(c2_, xq[mt][2], d, 0, 0, 0);    \
            d = __builtin_amdgcn_mfma_f32_16x16x32_bf16(c3_, xq[mt][3], d, 0, 0, 0);    \
            _Pragma("unroll")                                                           \
            for (int j = 0; j < 4; ++j) {                                               \
                float sj = d[j];                                                        \
                v2[mt] = __builtin_amdgcn_fmed3f(v1[mt], v2[mt], sj);                   \
                bool cc = sj > v1[mt];                                                  \
                v1[mt] = fmaxf(v1[mt], sj);                                             \
                i1[mt] = cc ? (sbase + j) : i1[mt];                                     \
            }                                                                           \
        }                                                                               \
    } while (0)

    // ---- main loop: 32 iters x 2 tiles; static a/b buffers, no rotation movs ----
    short8 a0 = PXg[lane], a1 = PXg[64 + lane], a2 = PXg[128 + lane], a3 = PXg[192 + lane];
    short8 b0, b1, b2, b3;
    #pragma unroll 1
    for (int it = 0; it < 32; ++it) {
        const int st0 = 2 * it, st1 = 2 * it + 1;
        {
            const short8* pn = PXg + (size_t)st1 * 256 + lane;
            b0 = pn[0]; b1 = pn[64]; b2 = pn[128]; b3 = pn[192];
        }
        COMPTILE(a0, a1, a2, a3, st0);
        if (it < 31) {
            const short8* pn = PXg + (size_t)(st0 + 2) * 256 + lane;
            a0 = pn[0]; a1 = pn[64]; a2 = pn[128]; a3 = pn[192];
        }
        COMPTILE(b0, b1, b2, b3, st1);
    }
#undef COMPTILE

    // ---- cross-lane merge; write idx|flag straight to global (no LDS, no fp64) ----
    int* slotbase = (int*)(out + (size_t)n * CT + (size_t)g * K * TP);
    #pragma unroll
    for (int mt = 0; mt < 2; ++mt) {
        float a1v = v1[mt], a2v = v2[mt];
        int ii = i1[mt];
        #pragma unroll
        for (int off = 16; off < 64; off <<= 1) {
            float p1 = __shfl_xor(a1v, off);
            float p2 = __shfl_xor(a2v, off);
            int   pi = __shfl_xor(ii, off);
            float lo = fminf(a1v, p1);
            a2v = fmaxf(fmaxf(a2v, p2), lo);
            bool take = (p1 > a1v) || (p1 == a1v && pi < ii);
            ii = take ? pi : ii;
            a1v = fmaxf(a1v, p1);
        }
        if (lane < 16) {
            unsigned int val = (unsigned int)ii | ((a1v - a2v < MARGIN) ? FLAGBIT : 0u);
            slotbase[tp0 + mt * 16 + lane] = (int)val;
        }
    }
}

// ==== Kernel C (fixup): rare exact fp64 rescan, float4 loads + unrolled chains ====
__global__ __launch_bounds__(256, 2) void vq_fix(
        const float* __restrict__ z, const float* __restrict__ cb,
        float* __restrict__ out) {
    __shared__ float sXq[4][K];

    const int lane = threadIdx.x & 63;
    const int w    = threadIdx.x >> 6;
    const int gq0  = (blockIdx.x * 4 + w) * 64;     // first query of this wave
    const int g    = gq0 >> 17;                     // M = 2^17
    const int mm   = gq0 & (M - 1);
    const int n    = mm >> 12;
    const int tp0  = mm & 4095;

    const float* zg  = z + (size_t)n * CT + (size_t)g * K * TP;
    const float* cbg = cb + (size_t)g * S * K;
    int* slotbase = (int*)(out + (size_t)n * CT + (size_t)g * K * TP);

    unsigned int val = (unsigned int)slotbase[tp0 + lane];
    unsigned long long mask = __ballot((val & FLAGBIT) != 0u);
    while (mask) {
        int qq = __ffsll((unsigned long long)mask) - 1; mask &= mask - 1;
        int tpq = tp0 + qq;
        __threadfence_block();
        if (lane < K) sXq[w][lane] = zg[(size_t)lane * TP + tpq];
        __threadfence_block();
        double bestv = 1e300; int besti = 0;
        #pragma unroll 2
        for (int si = 0; si < 16; ++si) {
            int s = lane * 16 + si;
            const f32x4* cr4 = (const f32x4*)(cbg + (size_t)s * K);
            f32x4 cv[10];
            #pragma unroll
            for (int i = 0; i < 10; ++i) cv[i] = cr4[i];   // issue all loads up-front
            double acc = 0.0, en = 0.0;
            #pragma unroll
            for (int i = 0; i < 10; ++i) {
                #pragma unroll
                for (int c = 0; c < 4; ++c) {
                    double ev = (double)cv[i][c];
                    acc = fma(ev, (double)sXq[w][i * 4 + c], acc);
                    en  = fma(ev, ev, en);
                }
            }
            double sc = 0.5 * en - acc;
            if (sc < bestv) { bestv = sc; besti = s; }
        }
        #pragma unroll
        for (int off = 1; off < 64; off <<= 1) {
            double pv = __shfl_xor(bestv, off);
            int    pi = __shfl_xor(besti, off);
            if (pv < bestv || (pv == bestv && pi < besti)) { bestv = pv; besti = pi; }
        }
        if (lane == 0) slotbase[tpq] = besti;       // clears flag
    }
}

// ==== Kernel B (gather): 4 queries/thread; int4 idx, float4 stores via 4x4 transpose ====
__global__ __launch_bounds__(256) void vq_gather(
        const float* __restrict__ z, const float* __restrict__ cb,
        float* __restrict__ out, double* __restrict__ loss) {
    const int q0 = (blockIdx.x * 256 + threadIdx.x) * 4;   // [0, 3*M), step 4
    const int g = q0 >> 17;                                // M = 2^17
    const int m = q0 & (M - 1);
    const int n = m >> 12;
    const int tp = m & 4095;                               // multiple of 4

    float* base = out + (size_t)n * CT + (size_t)g * K * TP;
    const int4 idx4 = *(const int4*)((const int*)base + tp);
    const float* cbg = cb + (size_t)g * S * K;
    const f32x4* c0 = (const f32x4*)(cbg + (size_t)(idx4.x & 1023) * K);
    const f32x4* c1 = (const f32x4*)(cbg + (size_t)(idx4.y & 1023) * K);
    const f32x4* c2 = (const f32x4*)(cbg + (size_t)(idx4.z & 1023) * K);
    const f32x4* c3 = (const f32x4*)(cbg + (size_t)(idx4.w & 1023) * K);
    const float* zr = z + (size_t)n * CT + (size_t)g * K * TP + tp;

    double lsum = 0.0;
    #pragma unroll
    for (int i = 0; i < 10; ++i) {
        f32x4 a = c0[i], b = c1[i], c = c2[i], d = c3[i];
        #pragma unroll
        for (int cc = 0; cc < 4; ++cc) {
            const int k = i * 4 + cc;
            f32x4 sv;
            sv[0] = a[cc]; sv[1] = b[cc]; sv[2] = c[cc]; sv[3] = d[cc];
            *(f32x4*)(base + (size_t)k * TP + tp) = sv;
            if (g == 2) {
                f32x4 xv = *(const f32x4*)(zr + (size_t)k * TP);
                #pragma unroll
                for (int j = 0; j < 4; ++j) {
                    double dd = (double)sv[j] - (double)xv[j];
                    lsum = fma(dd, dd, lsum);
                }
            }
        }
    }

    if (g == 2) {
        #pragma unroll
        for (int off = 1; off < 64; off <<= 1)
            lsum += __shfl_xor(lsum, off);
        if ((threadIdx.x & 63) == 0) atomicAdd(loss, lsum);
    }
}

// ---------------- finalize: scalar loss ----------------
__global__ void vq_fin_kernel(const double* __restrict__ loss, float* __restrict__ out) {
    out[OUT_Q] = (float)(0.25 * (*loss) / (double)((long long)M * K));
}

extern "C" void kernel_launch(void* const* d_in, const int* in_sizes, int n_in,
                              void* d_out, int out_size, void* d_ws, size_t ws_size,
                              hipStream_t stream) {
    const float* z  = (const float*)d_in[0];
    const float* cb = (const float*)d_in[1];
    float* out = (float*)d_out;

    char* ws = (char*)d_ws;
    double* loss = (double*)(ws + WS_LOSS);
    float*  e2   = (float*)(ws + WS_E2);
    short8* PX   = (short8*)(ws + WS_PX);

    vq_prep_frag<<<dim3(48), dim3(256), 0, stream>>>(cb, PX, e2, loss);
    vq_search<<<dim3(3072), dim3(256), 0, stream>>>(z, PX, e2, out);
    vq_fix<<<dim3((G * M) / 256), dim3(256), 0, stream>>>(z, cb, out);
    vq_gather<<<dim3((G * M) / 1024), dim3(256), 0, stream>>>(z, cb, out, loss);
    vq_fin_kernel<<<dim3(1), dim3(1), 0, stream>>>(loss, out);
}

// Round 30
// 200.983 us; speedup vs baseline: 2.3219x; 1.0756x over previous
//
#include <hip/hip_runtime.h>

#define G 3
#define K 40
#define S 1024
#define NB 32
#define CH 30
#define T 16384
#define TP 4096
#define M 131072           // NB*TP
#define CT (CH*T)          // 491520
#define OUT_Q (NB*CH*T)    // 15728640
#define MARGIN 4e-3f
#define FLAGBIT 0x40000000u

typedef __attribute__((ext_vector_type(8))) short short8;
typedef __attribute__((ext_vector_type(4))) float f32x4;

// ---- workspace layout ----
#define WS_LOSS 0
#define WS_E2   64                        // float[3][1024] = 12288 B
#define WS_PX   12352                     // short8[3*64*4*64] = 786432 B (end 798784)

static __device__ __forceinline__ unsigned short f2bf(float f) {
    union { float f; unsigned int u; } v; v.f = f;
    unsigned int u = v.u;
    return (unsigned short)((u + 0x7fffu + ((u >> 16) & 1u)) >> 16);   // RNE
}
static __device__ __forceinline__ float bf2f(unsigned short h) {
    union { unsigned int u; float f; } v; v.u = ((unsigned int)h) << 16;
    return v.f;
}

// Slot map: kappa = 32*m + 8*lgrp + j over virtual K=128.
//   [0,40): (eh,xh)  [40,80): (el,xh)  [80,120): (eh,xl)  [120,128): 0

// ================= prep: packed split fragments (interleaved) + e2 + loss zero =================
__global__ void vq_prep_frag(const float* __restrict__ cb, short8* __restrict__ PX,
                             float* __restrict__ e2, double* __restrict__ loss) {
    int t = blockIdx.x * 256 + threadIdx.x;      // [0, 3*64*64)
    if (t == 0) *loss = 0.0;
    if (t >= G * 64 * 64) return;
    const int lane = t & 63;
    const int st   = (t >> 6) & 63;
    const int g    = t >> 12;
    const int lmod = lane & 15, lgrp = lane >> 4;
    const int s0   = st * 16;
    const float* cbg = cb + (size_t)g * S * K;

    if (lane < 16) {
        const float* row = cbg + (size_t)(s0 + lane) * K;
        float acc = 0.f;
        #pragma unroll
        for (int k = 0; k < K; ++k) acc = fmaf(row[k], row[k], acc);
        e2[g * S + s0 + lane] = -0.5f * acc;     // maximize D = x.e - 0.5||e||^2
    }

    // A-operand layout (rounds 4-29 verified): lane holds row = lane&15, k' = 8*lgrp + j
    const float* crow = cbg + (size_t)(s0 + lmod) * K;
    #pragma unroll
    for (int m = 0; m < 4; ++m) {
        short8 P;
        #pragma unroll
        for (int j = 0; j < 8; ++j) {
            int kap = 32 * m + 8 * lgrp + j;
            bool valid = kap < 120;
            int d = (kap < 40) ? kap : ((kap < 80) ? kap - 40 : kap - 80);
            float v = valid ? crow[d] : 0.f;
            unsigned short hh = f2bf(v);
            unsigned short ll = f2bf(v - bf2f(hh));
            bool low = (kap >= 40) && (kap < 80);
            P[j] = (short)(low ? ll : hh);
        }
        PX[(((size_t)(g * 64 + st)) * 4 + m) * 64 + lane] = P;
    }
}

// ==== Kernel A (search): LDS-shared PX (r14 loop structure), direct merge epilogue ====
__global__ __launch_bounds__(256, 3) void vq_search(
        const float* __restrict__ z, const short8* __restrict__ PX,
        const float* __restrict__ e2, float* __restrict__ out) {
    __shared__ short8 frag[2][2][4][64];        // [buf][sub][chunk][lane] = 16 KB
    __shared__ float  sE2[S];                   // 4 KB

    const int lane = threadIdx.x & 63;
    const int w    = threadIdx.x >> 6;
    const int g    = blockIdx.x >> 9;                       // 512 blocks per group
    const int qbase = ((blockIdx.x & 511) << 8) + (w << 6); // 64 queries per wave
    const int n    = qbase >> 12;
    const int tp0  = qbase & 4095;
    const int lmod = lane & 15, lgrp = lane >> 4;

    const float* zg  = z + (size_t)n * CT + (size_t)g * K * TP;
    const float* e2g = e2 + g * S;
    // wave w stages chunk w: tile st lives at PXg[(st*4 + w)*64 + lane]
    const short8* srcW = PX + ((size_t)g * 64) * 4 * 64 + w * 64 + lane;

    // ---- e2 into LDS (all threads) ----
    *(f32x4*)(sE2 + threadIdx.x * 4) = *(const f32x4*)(e2g + threadIdx.x * 4);

    // ---- packed x fragments in registers/AGPRs: 4 m-tiles of 16 queries ----
    short8 xq[4][4];
    #pragma unroll
    for (int mt = 0; mt < 4; ++mt) {
        int tp = tp0 + mt * 16 + lmod;
        #pragma unroll
        for (int m = 0; m < 4; ++m) {
            short8 xb;
            #pragma unroll
            for (int j = 0; j < 8; ++j) {
                int kap = 32 * m + 8 * lgrp + j;
                bool valid = kap < 120;
                int d = (kap < 40) ? kap : ((kap < 80) ? kap - 40 : kap - 80);
                float v = valid ? zg[(size_t)d * TP + tp] : 0.f;
                unsigned short hh = f2bf(v);
                unsigned short ll = f2bf(v - bf2f(hh));
                bool low = (kap >= 80) && (kap < 120);
                xb[j] = (short)(low ? ll : hh);
            }
            xq[mt][m] = xb;
        }
    }

    float v1[4], v2[4]; int i1[4];
    #pragma unroll
    for (int mt = 0; mt < 4; ++mt) { v1[mt] = -3.4e38f; v2[mt] = -3.4e38f; i1[mt] = 0; }

    // ---- prologue: stage s-tiles 0,1 into buf 0 (each wave its chunk) ----
    frag[0][0][w][lane] = srcW[0];
    frag[0][1][w][lane] = srcW[256];
    __syncthreads();

    // ---- main loop: 32 iterations x 2 s-tiles, one barrier per iteration ----
    #pragma unroll 1
    for (int it = 0; it < 32; ++it) {
        const int cbuf = it & 1, nbuf = cbuf ^ 1;
        short8 nxtA, nxtB;
        if (it < 31) {
            nxtA = srcW[(size_t)(2 * it + 2) * 256];    // issue early (VMEM)
            nxtB = srcW[(size_t)(2 * it + 3) * 256];
        }

        #pragma unroll
        for (int sub = 0; sub < 2; ++sub) {
            const int st = 2 * it + sub;
            short8 p0 = frag[cbuf][sub][0][lane];
            short8 p1 = frag[cbuf][sub][1][lane];
            short8 p2 = frag[cbuf][sub][2][lane];
            short8 p3 = frag[cbuf][sub][3][lane];
            f32x4 e2v = *(const f32x4*)(sE2 + st * 16 + lgrp * 4);
            const int sbase = st * 16 + lgrp * 4;

            #pragma unroll
            for (int mt = 0; mt < 4; ++mt) {
                f32x4 d = __builtin_amdgcn_mfma_f32_16x16x32_bf16(p0, xq[mt][0], e2v, 0, 0, 0);
                d = __builtin_amdgcn_mfma_f32_16x16x32_bf16(p1, xq[mt][1], d, 0, 0, 0);
                d = __builtin_amdgcn_mfma_f32_16x16x32_bf16(p2, xq[mt][2], d, 0, 0, 0);
                d = __builtin_amdgcn_mfma_f32_16x16x32_bf16(p3, xq[mt][3], d, 0, 0, 0);
                #pragma unroll
                for (int j = 0; j < 4; ++j) {
                    float sj = d[j];
                    v2[mt] = __builtin_amdgcn_fmed3f(v1[mt], v2[mt], sj);  // 2nd-largest
                    bool cc = sj > v1[mt];
                    v1[mt] = fmaxf(v1[mt], sj);
                    i1[mt] = cc ? (sbase + j) : i1[mt];
                }
            }
        }

        if (it < 31) {
            frag[nbuf][0][w][lane] = nxtA;       // write-late
            frag[nbuf][1][w][lane] = nxtB;
        }
        __syncthreads();
    }

    // ---- cross-lane merge; write idx|flag straight to global (no LDS, no fp64) ----
    int* slotbase = (int*)(out + (size_t)n * CT + (size_t)g * K * TP);
    #pragma unroll
    for (int mt = 0; mt < 4; ++mt) {
        float a1v = v1[mt], a2v = v2[mt];
        int ii = i1[mt];
        #pragma unroll
        for (int off = 16; off < 64; off <<= 1) {
            float p1 = __shfl_xor(a1v, off);
            float p2 = __shfl_xor(a2v, off);
            int   pi = __shfl_xor(ii, off);
            float lo = fminf(a1v, p1);
            a2v = fmaxf(fmaxf(a2v, p2), lo);
            bool take = (p1 > a1v) || (p1 == a1v && pi < ii);
            ii = take ? pi : ii;
            a1v = fmaxf(a1v, p1);
        }
        if (lane < 16) {
            unsigned int val = (unsigned int)ii | ((a1v - a2v < MARGIN) ? FLAGBIT : 0u);
            slotbase[tp0 + mt * 16 + lane] = (int)val;
        }
    }
}

// ==== Kernel C (fixup): rare exact fp64 rescan, float4 loads + unrolled chains ====
__global__ __launch_bounds__(256, 2) void vq_fix(
        const float* __restrict__ z, const float* __restrict__ cb,
        float* __restrict__ out) {
    __shared__ float sXq[4][K];

    const int lane = threadIdx.x & 63;
    const int w    = threadIdx.x >> 6;
    const int gq0  = (blockIdx.x * 4 + w) * 64;     // first query of this wave
    const int g    = gq0 >> 17;                     // M = 2^17
    const int mm   = gq0 & (M - 1);
    const int n    = mm >> 12;
    const int tp0  = mm & 4095;

    const float* zg  = z + (size_t)n * CT + (size_t)g * K * TP;
    const float* cbg = cb + (size_t)g * S * K;
    int* slotbase = (int*)(out + (size_t)n * CT + (size_t)g * K * TP);

    unsigned int val = (unsigned int)slotbase[tp0 + lane];
    unsigned long long mask = __ballot((val & FLAGBIT) != 0u);
    while (mask) {
        int qq = __ffsll((unsigned long long)mask) - 1; mask &= mask - 1;
        int tpq = tp0 + qq;
        __threadfence_block();
        if (lane < K) sXq[w][lane] = zg[(size_t)lane * TP + tpq];
        __threadfence_block();
        double bestv = 1e300; int besti = 0;
        #pragma unroll 2
        for (int si = 0; si < 16; ++si) {
            int s = lane * 16 + si;
            const f32x4* cr4 = (const f32x4*)(cbg + (size_t)s * K);
            f32x4 cv[10];
            #pragma unroll
            for (int i = 0; i < 10; ++i) cv[i] = cr4[i];   // issue all loads up-front
            double acc = 0.0, en = 0.0;
            #pragma unroll
            for (int i = 0; i < 10; ++i) {
                #pragma unroll
                for (int c = 0; c < 4; ++c) {
                    double ev = (double)cv[i][c];
                    acc = fma(ev, (double)sXq[w][i * 4 + c], acc);
                    en  = fma(ev, ev, en);
                }
            }
            double sc = 0.5 * en - acc;
            if (sc < bestv) { bestv = sc; besti = s; }
        }
        #pragma unroll
        for (int off = 1; off < 64; off <<= 1) {
            double pv = __shfl_xor(bestv, off);
            int    pi = __shfl_xor(besti, off);
            if (pv < bestv || (pv == bestv && pi < besti)) { bestv = pv; besti = pi; }
        }
        if (lane == 0) slotbase[tpq] = besti;       // clears flag
    }
}

// ==== Kernel B (gather): 4 queries/thread; int4 idx, float4 stores via 4x4 transpose ====
__global__ __launch_bounds__(256) void vq_gather(
        const float* __restrict__ z, const float* __restrict__ cb,
        float* __restrict__ out, double* __restrict__ loss) {
    const int q0 = (blockIdx.x * 256 + threadIdx.x) * 4;   // [0, 3*M), step 4
    const int g = q0 >> 17;                                // M = 2^17
    const int m = q0 & (M - 1);
    const int n = m >> 12;
    const int tp = m & 4095;                               // multiple of 4

    float* base = out + (size_t)n * CT + (size_t)g * K * TP;
    const int4 idx4 = *(const int4*)((const int*)base + tp);
    const float* cbg = cb + (size_t)g * S * K;
    const f32x4* c0 = (const f32x4*)(cbg + (size_t)(idx4.x & 1023) * K);
    const f32x4* c1 = (const f32x4*)(cbg + (size_t)(idx4.y & 1023) * K);
    const f32x4* c2 = (const f32x4*)(cbg + (size_t)(idx4.z & 1023) * K);
    const f32x4* c3 = (const f32x4*)(cbg + (size_t)(idx4.w & 1023) * K);
    const float* zr = z + (size_t)n * CT + (size_t)g * K * TP + tp;

    double lsum = 0.0;
    #pragma unroll
    for (int i = 0; i < 10; ++i) {
        f32x4 a = c0[i], b = c1[i], c = c2[i], d = c3[i];
        #pragma unroll
        for (int cc = 0; cc < 4; ++cc) {
            const int k = i * 4 + cc;
            f32x4 sv;
            sv[0] = a[cc]; sv[1] = b[cc]; sv[2] = c[cc]; sv[3] = d[cc];
            *(f32x4*)(base + (size_t)k * TP + tp) = sv;
            if (g == 2) {
                f32x4 xv = *(const f32x4*)(zr + (size_t)k * TP);
                #pragma unroll
                for (int j = 0; j < 4; ++j) {
                    double dd = (double)sv[j] - (double)xv[j];
                    lsum = fma(dd, dd, lsum);
                }
            }
        }
    }

    if (g == 2) {
        #pragma unroll
        for (int off = 1; off < 64; off <<= 1)
            lsum += __shfl_xor(lsum, off);
        if ((threadIdx.x & 63) == 0) atomicAdd(loss, lsum);
    }
}

// ---------------- finalize: scalar loss ----------------
__global__ void vq_fin_kernel(const double* __restrict__ loss, float* __restrict__ out) {
    out[OUT_Q] = (float)(0.25 * (*loss) / (double)((long long)M * K));
}

extern "C" void kernel_launch(void* const* d_in, const int* in_sizes, int n_in,
                              void* d_out, int out_size, void* d_ws, size_t ws_size,
                              hipStream_t stream) {
    const float* z  = (const float*)d_in[0];
    const float* cb = (const float*)d_in[1];
    float* out = (float*)d_out;

    char* ws = (char*)d_ws;
    double* loss = (double*)(ws + WS_LOSS);
    float*  e2   = (float*)(ws + WS_E2);
    short8* PX   = (short8*)(ws + WS_PX);

    vq_prep_frag<<<dim3(48), dim3(256), 0, stream>>>(cb, PX, e2, loss);
    vq_search<<<dim3(1536), dim3(256), 0, stream>>>(z, PX, e2, out);
    vq_fix<<<dim3((G * M) / 256), dim3(256), 0, stream>>>(z, cb, out);
    vq_gather<<<dim3((G * M) / 1024), dim3(256), 0, stream>>>(z, cb, out, loss);
    vq_fin_kernel<<<dim3(1), dim3(1), 0, stream>>>(loss, out);
}

// Round 31
// 200.918 us; speedup vs baseline: 2.3226x; 1.0003x over previous
//
#include <hip/hip_runtime.h>

#define G 3
#define K 40
#define S 1024
#define NB 32
#define CH 30
#define T 16384
#define TP 4096
#define M 131072           // NB*TP
#define CT (CH*T)          // 491520
#define OUT_Q (NB*CH*T)    // 15728640
#define MARGIN 4e-3f
#define FLAGBIT 0x40000000u

typedef __attribute__((ext_vector_type(8))) short short8;
typedef __attribute__((ext_vector_type(4))) float f32x4;

// ---- workspace layout ----
#define WS_LOSS 0
#define WS_E2   64                        // float[3][1024] = 12288 B
#define WS_PX   12352                     // short8[3*64*4*64] = 786432 B (end 798784)

static __device__ __forceinline__ unsigned short f2bf(float f) {
    union { float f; unsigned int u; } v; v.f = f;
    unsigned int u = v.u;
    return (unsigned short)((u + 0x7fffu + ((u >> 16) & 1u)) >> 16);   // RNE
}
static __device__ __forceinline__ float bf2f(unsigned short h) {
    union { unsigned int u; float f; } v; v.u = ((unsigned int)h) << 16;
    return v.f;
}

// Slot map: kappa = 32*m + 8*lgrp + j over virtual K=128.
//   [0,40): (eh,xh)  [40,80): (el,xh)  [80,120): (eh,xl)  [120,128): 0

// ================= prep: packed split fragments (interleaved) + e2 + loss zero =================
__global__ void vq_prep_frag(const float* __restrict__ cb, short8* __restrict__ PX,
                             float* __restrict__ e2, double* __restrict__ loss) {
    int t = blockIdx.x * 256 + threadIdx.x;      // [0, 3*64*64)
    if (t == 0) *loss = 0.0;
    if (t >= G * 64 * 64) return;
    const int lane = t & 63;
    const int st   = (t >> 6) & 63;
    const int g    = t >> 12;
    const int lmod = lane & 15, lgrp = lane >> 4;
    const int s0   = st * 16;
    const float* cbg = cb + (size_t)g * S * K;

    if (lane < 16) {
        const float* row = cbg + (size_t)(s0 + lane) * K;
        float acc = 0.f;
        #pragma unroll
        for (int k = 0; k < K; ++k) acc = fmaf(row[k], row[k], acc);
        e2[g * S + s0 + lane] = -0.5f * acc;     // maximize D = x.e - 0.5||e||^2
    }

    // A-operand layout (rounds 4-30 verified): lane holds row = lane&15, k' = 8*lgrp + j
    const float* crow = cbg + (size_t)(s0 + lmod) * K;
    #pragma unroll
    for (int m = 0; m < 4; ++m) {
        short8 P;
        #pragma unroll
        for (int j = 0; j < 8; ++j) {
            int kap = 32 * m + 8 * lgrp + j;
            bool valid = kap < 120;
            int d = (kap < 40) ? kap : ((kap < 80) ? kap - 40 : kap - 80);
            float v = valid ? crow[d] : 0.f;
            unsigned short hh = f2bf(v);
            unsigned short ll = f2bf(v - bf2f(hh));
            bool low = (kap >= 40) && (kap < 80);
            P[j] = (short)(low ? ll : hh);
        }
        PX[(((size_t)(g * 64 + st)) * 4 + m) * 64 + lane] = P;
    }
}

// ==== Kernel A (search): r30-proven — LDS-shared PX, direct merge epilogue ====
__global__ __launch_bounds__(256, 3) void vq_search(
        const float* __restrict__ z, const short8* __restrict__ PX,
        const float* __restrict__ e2, float* __restrict__ out) {
    __shared__ short8 frag[2][2][4][64];        // [buf][sub][chunk][lane] = 16 KB
    __shared__ float  sE2[S];                   // 4 KB

    const int lane = threadIdx.x & 63;
    const int w    = threadIdx.x >> 6;
    const int g    = blockIdx.x >> 9;                       // 512 blocks per group
    const int qbase = ((blockIdx.x & 511) << 8) + (w << 6); // 64 queries per wave
    const int n    = qbase >> 12;
    const int tp0  = qbase & 4095;
    const int lmod = lane & 15, lgrp = lane >> 4;

    const float* zg  = z + (size_t)n * CT + (size_t)g * K * TP;
    const float* e2g = e2 + g * S;
    const short8* srcW = PX + ((size_t)g * 64) * 4 * 64 + w * 64 + lane;

    // ---- e2 into LDS (all threads) ----
    *(f32x4*)(sE2 + threadIdx.x * 4) = *(const f32x4*)(e2g + threadIdx.x * 4);

    // ---- packed x fragments in registers/AGPRs: 4 m-tiles of 16 queries ----
    short8 xq[4][4];
    #pragma unroll
    for (int mt = 0; mt < 4; ++mt) {
        int tp = tp0 + mt * 16 + lmod;
        #pragma unroll
        for (int m = 0; m < 4; ++m) {
            short8 xb;
            #pragma unroll
            for (int j = 0; j < 8; ++j) {
                int kap = 32 * m + 8 * lgrp + j;
                bool valid = kap < 120;
                int d = (kap < 40) ? kap : ((kap < 80) ? kap - 40 : kap - 80);
                float v = valid ? zg[(size_t)d * TP + tp] : 0.f;
                unsigned short hh = f2bf(v);
                unsigned short ll = f2bf(v - bf2f(hh));
                bool low = (kap >= 80) && (kap < 120);
                xb[j] = (short)(low ? ll : hh);
            }
            xq[mt][m] = xb;
        }
    }

    float v1[4], v2[4]; int i1[4];
    #pragma unroll
    for (int mt = 0; mt < 4; ++mt) { v1[mt] = -3.4e38f; v2[mt] = -3.4e38f; i1[mt] = 0; }

    // ---- prologue: stage s-tiles 0,1 into buf 0 (each wave its chunk) ----
    frag[0][0][w][lane] = srcW[0];
    frag[0][1][w][lane] = srcW[256];
    __syncthreads();

    // ---- main loop: 32 iterations x 2 s-tiles, one barrier per iteration ----
    #pragma unroll 1
    for (int it = 0; it < 32; ++it) {
        const int cbuf = it & 1, nbuf = cbuf ^ 1;
        short8 nxtA, nxtB;
        if (it < 31) {
            nxtA = srcW[(size_t)(2 * it + 2) * 256];    // issue early (VMEM)
            nxtB = srcW[(size_t)(2 * it + 3) * 256];
        }

        #pragma unroll
        for (int sub = 0; sub < 2; ++sub) {
            const int st = 2 * it + sub;
            short8 p0 = frag[cbuf][sub][0][lane];
            short8 p1 = frag[cbuf][sub][1][lane];
            short8 p2 = frag[cbuf][sub][2][lane];
            short8 p3 = frag[cbuf][sub][3][lane];
            f32x4 e2v = *(const f32x4*)(sE2 + st * 16 + lgrp * 4);
            const int sbase = st * 16 + lgrp * 4;

            #pragma unroll
            for (int mt = 0; mt < 4; ++mt) {
                f32x4 d = __builtin_amdgcn_mfma_f32_16x16x32_bf16(p0, xq[mt][0], e2v, 0, 0, 0);
                d = __builtin_amdgcn_mfma_f32_16x16x32_bf16(p1, xq[mt][1], d, 0, 0, 0);
                d = __builtin_amdgcn_mfma_f32_16x16x32_bf16(p2, xq[mt][2], d, 0, 0, 0);
                d = __builtin_amdgcn_mfma_f32_16x16x32_bf16(p3, xq[mt][3], d, 0, 0, 0);
                #pragma unroll
                for (int j = 0; j < 4; ++j) {
                    float sj = d[j];
                    v2[mt] = __builtin_amdgcn_fmed3f(v1[mt], v2[mt], sj);  // 2nd-largest
                    bool cc = sj > v1[mt];
                    v1[mt] = fmaxf(v1[mt], sj);
                    i1[mt] = cc ? (sbase + j) : i1[mt];
                }
            }
        }

        if (it < 31) {
            frag[nbuf][0][w][lane] = nxtA;       // write-late
            frag[nbuf][1][w][lane] = nxtB;
        }
        __syncthreads();
    }

    // ---- cross-lane merge; write idx|flag straight to global (no LDS, no fp64) ----
    int* slotbase = (int*)(out + (size_t)n * CT + (size_t)g * K * TP);
    #pragma unroll
    for (int mt = 0; mt < 4; ++mt) {
        float a1v = v1[mt], a2v = v2[mt];
        int ii = i1[mt];
        #pragma unroll
        for (int off = 16; off < 64; off <<= 1) {
            float p1 = __shfl_xor(a1v, off);
            float p2 = __shfl_xor(a2v, off);
            int   pi = __shfl_xor(ii, off);
            float lo = fminf(a1v, p1);
            a2v = fmaxf(fmaxf(a2v, p2), lo);
            bool take = (p1 > a1v) || (p1 == a1v && pi < ii);
            ii = take ? pi : ii;
            a1v = fmaxf(a1v, p1);
        }
        if (lane < 16) {
            unsigned int val = (unsigned int)ii | ((a1v - a2v < MARGIN) ? FLAGBIT : 0u);
            slotbase[tp0 + mt * 16 + lane] = (int)val;
        }
    }
}

// ==== Kernel B (gather+fix): phase 1 rare fp64 rescan, phase 2 transpose gather ====
__global__ __launch_bounds__(256, 2) void vq_gatherfix(
        const float* __restrict__ z, const float* __restrict__ cb,
        float* __restrict__ out, double* __restrict__ loss) {
    __shared__ float sXq[4][K];

    const int lane = threadIdx.x & 63;
    const int w    = threadIdx.x >> 6;
    const int qblk = blockIdx.x * 1024;             // block owns 1024 queries (same g,n)
    const int g    = qblk >> 17;                    // M = 2^17
    const int mm   = qblk & (M - 1);
    const int n    = mm >> 12;
    const int tpb  = mm & 4095;                     // multiple of 1024

    const float* zg  = z + (size_t)n * CT + (size_t)g * K * TP;
    const float* cbg = cb + (size_t)g * S * K;
    float* base = out + (size_t)n * CT + (size_t)g * K * TP;
    int* slotbase = (int*)base;

    // ---- phase 1: rescan flagged queries; wave w owns [w*256, w*256+256) ----
    #pragma unroll 1
    for (int rep = 0; rep < 4; ++rep) {
        const int tw = tpb + w * 256 + rep * 64;    // wave-round base tp
        unsigned int val = (unsigned int)slotbase[tw + lane];
        unsigned long long mask = __ballot((val & FLAGBIT) != 0u);
        while (mask) {
            int qq = __ffsll((unsigned long long)mask) - 1; mask &= mask - 1;
            int tpq = tw + qq;
            __threadfence_block();
            if (lane < K) sXq[w][lane] = zg[(size_t)lane * TP + tpq];
            __threadfence_block();
            double bestv = 1e300; int besti = 0;
            #pragma unroll 2
            for (int si = 0; si < 16; ++si) {
                int s = lane * 16 + si;
                const f32x4* cr4 = (const f32x4*)(cbg + (size_t)s * K);
                f32x4 cv[10];
                #pragma unroll
                for (int i = 0; i < 10; ++i) cv[i] = cr4[i];
                double acc = 0.0, en = 0.0;
                #pragma unroll
                for (int i = 0; i < 10; ++i) {
                    #pragma unroll
                    for (int c = 0; c < 4; ++c) {
                        double ev = (double)cv[i][c];
                        acc = fma(ev, (double)sXq[w][i * 4 + c], acc);
                        en  = fma(ev, ev, en);
                    }
                }
                double sc = 0.5 * en - acc;
                if (sc < bestv) { bestv = sc; besti = s; }
            }
            #pragma unroll
            for (int off = 1; off < 64; off <<= 1) {
                double pv = __shfl_xor(bestv, off);
                int    pi = __shfl_xor(besti, off);
                if (pv < bestv || (pv == bestv && pi < besti)) { bestv = pv; besti = pi; }
            }
            if (lane == 0) slotbase[tpq] = besti;   // clears flag
        }
    }
    __threadfence_block();      // corrected slots visible block-wide
    __syncthreads();

    // ---- phase 2: gather 4 queries/thread (int4 idx, float4 stores via transpose) ----
    const int tp = tpb + threadIdx.x * 4;
    const int4 idx4 = *(const int4*)(slotbase + tp);
    const f32x4* c0 = (const f32x4*)(cbg + (size_t)(idx4.x & 1023) * K);
    const f32x4* c1 = (const f32x4*)(cbg + (size_t)(idx4.y & 1023) * K);
    const f32x4* c2 = (const f32x4*)(cbg + (size_t)(idx4.z & 1023) * K);
    const f32x4* c3 = (const f32x4*)(cbg + (size_t)(idx4.w & 1023) * K);
    const float* zr = zg + tp;

    double lsum = 0.0;
    #pragma unroll
    for (int i = 0; i < 10; ++i) {
        f32x4 a = c0[i], b = c1[i], c = c2[i], d = c3[i];
        #pragma unroll
        for (int cc = 0; cc < 4; ++cc) {
            const int k = i * 4 + cc;
            f32x4 sv;
            sv[0] = a[cc]; sv[1] = b[cc]; sv[2] = c[cc]; sv[3] = d[cc];
            *(f32x4*)(base + (size_t)k * TP + tp) = sv;
            if (g == 2) {
                f32x4 xv = *(const f32x4*)(zr + (size_t)k * TP);
                #pragma unroll
                for (int j = 0; j < 4; ++j) {
                    double dd = (double)sv[j] - (double)xv[j];
                    lsum = fma(dd, dd, lsum);
                }
            }
        }
    }

    if (g == 2) {
        #pragma unroll
        for (int off = 1; off < 64; off <<= 1)
            lsum += __shfl_xor(lsum, off);
        if (lane == 0) atomicAdd(loss, lsum);
    }
}

// ---------------- finalize: scalar loss ----------------
__global__ void vq_fin_kernel(const double* __restrict__ loss, float* __restrict__ out) {
    out[OUT_Q] = (float)(0.25 * (*loss) / (double)((long long)M * K));
}

extern "C" void kernel_launch(void* const* d_in, const int* in_sizes, int n_in,
                              void* d_out, int out_size, void* d_ws, size_t ws_size,
                              hipStream_t stream) {
    const float* z  = (const float*)d_in[0];
    const float* cb = (const float*)d_in[1];
    float* out = (float*)d_out;

    char* ws = (char*)d_ws;
    double* loss = (double*)(ws + WS_LOSS);
    float*  e2   = (float*)(ws + WS_E2);
    short8* PX   = (short8*)(ws + WS_PX);

    vq_prep_frag<<<dim3(48), dim3(256), 0, stream>>>(cb, PX, e2, loss);
    vq_search<<<dim3(1536), dim3(256), 0, stream>>>(z, PX, e2, out);
    vq_gatherfix<<<dim3((G * M) / 1024), dim3(256), 0, stream>>>(z, cb, out, loss);
    vq_fin_kernel<<<dim3(1), dim3(1), 0, stream>>>(loss, out);
}